// Round 8
// baseline (2326.707 us; speedup 1.0000x reference)
//
#include <hip/hip_runtime.h>
#include <hip/hip_fp8.h>
#include <stdint.h>

#define K_DIM 4096
#define N_DIM 4096
#define NKB   32     // number of 128-wide K scale blocks

using f32x4 = __attribute__((ext_vector_type(4))) float;
using i32x4 = __attribute__((ext_vector_type(4))) int;
using i32x8 = __attribute__((ext_vector_type(8))) int;

#define GLOAD_LDS16(g, l)                                                      \
    __builtin_amdgcn_global_load_lds(                                          \
        (const __attribute__((address_space(1))) unsigned int*)(g),            \
        (__attribute__((address_space(3))) unsigned int*)(l), 16, 0, 0)
#define GLOAD_LDS4(g, l)                                                       \
    __builtin_amdgcn_global_load_lds(                                          \
        (const __attribute__((address_space(1))) unsigned int*)(g),            \
        (__attribute__((address_space(3))) unsigned int*)(l), 4, 0, 0)

__device__ __forceinline__ uint8_t to_fp8(float v) {
    __hip_fp8_e4m3 q(v);   // OCP e4m3fn, RNE saturating
    return (uint8_t)q.__x;
}

// ---------------- activation quant: one wave per (m, kb); scales TRANSPOSED saT[kb][m] ----------------
__global__ __launch_bounds__(256) void act_quant_kernel(
    const float* __restrict__ x, uint8_t* __restrict__ xq,
    float* __restrict__ saT, int M)
{
    int gw   = blockIdx.x * 4 + (threadIdx.x >> 6);
    int lane = threadIdx.x & 63;
    int m    = gw >> 5;
    int kb   = gw & 31;
    size_t base = (size_t)m * K_DIM + kb * 128 + lane * 2;
    float2 v = *(const float2*)(x + base);
    float amax = fmaxf(fabsf(v.x), fabsf(v.y));
    #pragma unroll
    for (int o = 32; o >= 1; o >>= 1) amax = fmaxf(amax, __shfl_xor(amax, o));
    float s = amax / 448.0f;          // IEEE div, matches jnp exactly
    uchar2 q;
    q.x = to_fp8(v.x / s);
    q.y = to_fp8(v.y / s);
    *(uchar2*)(xq + base) = q;
    if (lane == 0) saT[(size_t)kb * M + m] = s;
}

// ---------------- weight quant ----------------
__global__ __launch_bounds__(256) void w_quant_kernel(
    const float* __restrict__ w, uint8_t* __restrict__ wq)
{
    size_t i = ((size_t)blockIdx.x * 256 + threadIdx.x) * 4;
    float4 v = *(const float4*)(w + i);
    uchar4 q;
    q.x = to_fp8(v.x); q.y = to_fp8(v.y); q.z = to_fp8(v.z); q.w = to_fp8(v.w);
    *(uchar4*)(wq + i) = q;
}

// ---------------- ratio pre-kernel (verified R2): telescoping rescale factors ----------------
// ra[sb][m]  = sb==0 ? 1 : saT[sb-1][m]/saT[sb][m]
// rwr[sb][nb]= sb==0 ? 1 : ws[nb][sb-1]/ws[nb][sb]
__global__ __launch_bounds__(256) void ratio_kernel(
    const float* __restrict__ saT, const float* __restrict__ ws,
    float* __restrict__ ra, float* __restrict__ rwr, int M)
{
    int idx = blockIdx.x * 256 + threadIdx.x;
    if (idx < 32 * M) {
        int sb = idx / M, m = idx - sb * M;
        float v = 1.0f;
        if (sb >= 1) v = saT[(size_t)(sb - 1) * M + m] / saT[(size_t)sb * M + m];
        ra[idx] = v;
    }
    if (idx < 32 * 32) {
        int sb = idx >> 5, nb = idx & 31;
        float v = 1.0f;
        if (sb >= 1) v = ws[nb * NKB + sb - 1] / ws[nb * NKB + sb];
        rwr[idx] = v;
    }
}

// ---------------- MX fp8 GEMM: 256x256 tile, BK=128, 4-phase, direct-accumulate ----------------
// LDS per buffer: A 32K | B 32K | ratios 1K -> 66560 B; x2 = 133120 B (1 block/CU)
#define LSA(b) ((b) * 66560)
#define LSB(b) ((b) * 66560 + 32768)
#define LSS(b) ((b) * 66560 + 65536)

__global__ __launch_bounds__(512)
__attribute__((amdgpu_waves_per_eu(2, 2)))
void fp8_gemm_mx6(
    const uint8_t* __restrict__ Aq, const uint8_t* __restrict__ Bq,
    const float* __restrict__ saT, const float* __restrict__ ra,
    const float* __restrict__ rwr, const float* __restrict__ wscale,
    float* __restrict__ C, int M)
{
    __shared__ __align__(16) uint8_t lds[133120];

    const int t    = threadIdx.x;
    const int lane = t & 63;
    const int lr   = lane & 15;
    const int lk   = lane >> 4;          // 0..3 -> k sub-block of 32
    const int wid  = t >> 6;
    const int wm   = wid >> 2;           // 0..1 : wave row half (128 rows)
    const int wn   = wid & 3;            // 0..3 : wave col quarter (64 cols)

    const int gridN = N_DIM / 256;       // 16
    int nwg = (M / 256) * gridN;         // 512, %8==0
    int cpx = nwg >> 3;
    int bid = blockIdx.x;
    int swz = (bid & 7) * cpx + (bid >> 3);   // bijective XCD swizzle
    const int m0 = (swz / gridN) * 256;
    const int n0 = (swz % gridN) * 256;
    const int nb = (n0 >> 7) + (wn >> 1);     // global wscale row (0..31)

    // staging map (proven R3/R5/R6): thread t -> row srow, phys 16B chunk (t&7);
    // source logical chunk ((t&7)^(srow&7)) => phys_chunk = logical ^ (row&7)
    const int srow = t >> 3;                       // 0..63 per pass
    const int scol = ((t & 7) ^ (srow & 7)) * 16;
    const uint8_t* gA = Aq + (size_t)(m0 + srow) * K_DIM + scol;
    const uint8_t* gB = Bq + (size_t)(n0 + srow) * K_DIM + scol;
    const int ldst = t * 16;                       // 8 KB per pass

    // fragment read swizzle: (row&7)==(lr&7)
    const int fsw = (lr & 7) << 4;
    const int c0  = (lk * 32) ^ fsw;

    f32x4 acc[8][4] = {};

    // ---- prologue: stage K-block 0 into buf 0 ----
    #pragma unroll
    for (int j = 0; j < 4; ++j) {
        GLOAD_LDS16(gA + (size_t)j * 64 * K_DIM, &lds[LSA(0) + j * 8192 + ldst]);
        GLOAD_LDS16(gB + (size_t)j * 64 * K_DIM, &lds[LSB(0) + j * 8192 + ldst]);
    }
    asm volatile("s_waitcnt vmcnt(0)" ::: "memory");
    __builtin_amdgcn_s_barrier();

    #pragma unroll 2
    for (int kb = 0; kb < NKB; ++kb) {
        const int cur = kb & 1;
        const int nxt = cur ^ 1;
        const int aB = LSA(cur), bB = LSB(cur), sB = LSS(cur);
        const int stage = (kb < NKB - 1);
        const size_t ko = (size_t)(kb + 1) * 128;
        const float rwc = kb ? rwr[kb * 32 + nb] : 1.0f;  // wave-uniform ratio

        #pragma unroll
        for (int ph = 0; ph < 4; ++ph) {
            const int mh = ph >> 1, nh = ph & 1;  // quadrant of wave tile

            // ---- 12x ds_read_b128 fragments + 4x ratio reads ----
            i32x8 af[4];
            i32x8 bfr[2];
            f32x4 ra4[4];
            #pragma unroll
            for (int mi = 0; mi < 4; ++mi) {
                int rb = aB + (wm * 128 + mh * 64 + mi * 16 + lr) * 128;
                i32x4 lo = *(const i32x4*)&lds[rb + c0];
                i32x4 hi = *(const i32x4*)&lds[rb + (c0 ^ 16)];
                af[mi] = __builtin_shufflevector(lo, hi, 0, 1, 2, 3, 4, 5, 6, 7);
            }
            #pragma unroll
            for (int ni = 0; ni < 2; ++ni) {
                int rb = bB + (wn * 64 + nh * 32 + ni * 16 + lr) * 128;
                i32x4 lo = *(const i32x4*)&lds[rb + c0];
                i32x4 hi = *(const i32x4*)&lds[rb + (c0 ^ 16)];
                bfr[ni] = __builtin_shufflevector(lo, hi, 0, 1, 2, 3, 4, 5, 6, 7);
            }
            if (kb) {
                #pragma unroll
                for (int mi = 0; mi < 4; ++mi)
                    ra4[mi] = *(const f32x4*)&lds[sB + (wm * 128 + mh * 64 + mi * 16 + lk * 4) * 4];
            }

            // ---- front-loaded staging for tile kb+1 (A in ph0, B+ratios in ph1) ----
            if (stage && ph == 0) {
                #pragma unroll
                for (int j = 0; j < 4; ++j)
                    GLOAD_LDS16(gA + ko + (size_t)j * 64 * K_DIM,
                                &lds[LSA(nxt) + j * 8192 + ldst]);
            }
            if (stage && ph == 1) {
                #pragma unroll
                for (int j = 0; j < 4; ++j)
                    GLOAD_LDS16(gB + ko + (size_t)j * 64 * K_DIM,
                                &lds[LSB(nxt) + j * 8192 + ldst]);
                if (wid < 4)
                    GLOAD_LDS4(ra + (size_t)(kb + 1) * M + m0 + wid * 64 + lane,
                               &lds[LSS(nxt) + wid * 256 + lane * 4]);
            }

            __builtin_amdgcn_s_barrier();
            asm volatile("s_waitcnt lgkmcnt(0)" ::: "memory");
            __builtin_amdgcn_sched_barrier(0);

            // ---- telescoped rescale of THIS quadrant (once per kb) ----
            if (kb) {
                #pragma unroll
                for (int mi = 0; mi < 4; ++mi) {
                    f32x4 sc = ra4[mi] * rwc;
                    acc[mh * 4 + mi][nh * 2 + 0] *= sc;
                    acc[mh * 4 + mi][nh * 2 + 1] *= sc;
                }
            }

            // ---- 8x mfma_scale K=128, accumulating IN PLACE (no bs temps) ----
            __builtin_amdgcn_s_setprio(1);
            #pragma unroll
            for (int mi = 0; mi < 4; ++mi)
                #pragma unroll
                for (int ni = 0; ni < 2; ++ni)
                    acc[mh * 4 + mi][nh * 2 + ni] =
                        __builtin_amdgcn_mfma_scale_f32_16x16x128_f8f6f4(
                            af[mi], bfr[ni], acc[mh * 4 + mi][nh * 2 + ni],
                            0, 0, 0, 0x7F7F7F7F, 0, 0x7F7F7F7F);
            __builtin_amdgcn_s_setprio(0);

            if (ph == 3) asm volatile("s_waitcnt vmcnt(0)" ::: "memory");
            __builtin_amdgcn_s_barrier();
        }
    }

    // ---- epilogue: out = acc * s31[m] * ws[nb][31]; C/D layout col=lane&15, row=lk*4+j ----
    const float ws31 = wscale[nb * NKB + 31];
    #pragma unroll
    for (int q = 0; q < 8; ++q) {
        int mh = q >> 2, mi = q & 3;
        f32x4 s31 = *(const f32x4*)(saT + (size_t)31 * M + m0 + wm * 128 + mh * 64 + mi * 16 + lk * 4);
        f32x4 sc = s31 * ws31;
        #pragma unroll
        for (int j = 0; j < 4; ++j) {
            int m = m0 + wm * 128 + mh * 64 + mi * 16 + lk * 4 + j;
            float* crow = C + (size_t)m * N_DIM + n0 + wn * 64;
            #pragma unroll
            for (int ni = 0; ni < 4; ++ni) {
                int nh = ni >> 1, nn = ni & 1;
                crow[nh * 32 + nn * 16 + lr] = acc[q][nh * 2 + nn][j] * sc[j];
            }
        }
    }
}

extern "C" void kernel_launch(void* const* d_in, const int* in_sizes, int n_in,
                              void* d_out, int out_size, void* d_ws, size_t ws_size,
                              hipStream_t stream) {
    const float* x      = (const float*)d_in[0];
    const float* w      = (const float*)d_in[1];
    const float* wscale = (const float*)d_in[2];
    float* out = (float*)d_out;
    int M = in_sizes[0] / K_DIM;                  // 8192

    // workspace: xq [M*K] | wq [N*K] | saT [32*M] | ra [32*M] | rwr [32*32]
    uint8_t* xq  = (uint8_t*)d_ws;
    uint8_t* wq  = xq + (size_t)M * K_DIM;
    float*   saT = (float*)(wq + (size_t)N_DIM * K_DIM);
    float*   ra  = saT + (size_t)NKB * M;
    float*   rwr = ra + (size_t)NKB * M;

    act_quant_kernel<<<M * NKB / 4, 256, 0, stream>>>(x, xq, saT, M);
    w_quant_kernel<<<((size_t)N_DIM * K_DIM) / 1024, 256, 0, stream>>>(w, wq);
    ratio_kernel<<<(32 * M + 255) / 256, 256, 0, stream>>>(saT, wscale, ra, rwr, M);

    int nwg = (M / 256) * (N_DIM / 256);
    fp8_gemm_mx6<<<nwg, 512, 0, stream>>>(xq, wq, saT, ra, rwr, wscale, out, M);
}

// Round 9
// 1846.146 us; speedup vs baseline: 1.2603x; 1.2603x over previous
//
#include <hip/hip_runtime.h>
#include <hip/hip_fp8.h>
#include <stdint.h>

#define K_DIM 4096
#define N_DIM 4096
#define NKB   32     // number of 128-wide K scale blocks

using f32x4 = __attribute__((ext_vector_type(4))) float;
using i32x4 = __attribute__((ext_vector_type(4))) int;
using i32x8 = __attribute__((ext_vector_type(8))) int;

#define GLOAD_LDS16(g, l)                                                      \
    __builtin_amdgcn_global_load_lds(                                          \
        (const __attribute__((address_space(1))) unsigned int*)(g),            \
        (__attribute__((address_space(3))) unsigned int*)(l), 16, 0, 0)
#define GLOAD_LDS4(g, l)                                                       \
    __builtin_amdgcn_global_load_lds(                                          \
        (const __attribute__((address_space(1))) unsigned int*)(g),            \
        (__attribute__((address_space(3))) unsigned int*)(l), 4, 0, 0)

__device__ __forceinline__ uint8_t to_fp8(float v) {
    __hip_fp8_e4m3 q(v);   // OCP e4m3fn, RNE saturating
    return (uint8_t)q.__x;
}

// ---------------- activation quant: one wave per (m, kb); scales TRANSPOSED saT[kb][m] ----------------
__global__ __launch_bounds__(256) void act_quant_kernel(
    const float* __restrict__ x, uint8_t* __restrict__ xq,
    float* __restrict__ saT, int M)
{
    int gw   = blockIdx.x * 4 + (threadIdx.x >> 6);
    int lane = threadIdx.x & 63;
    int m    = gw >> 5;
    int kb   = gw & 31;
    size_t base = (size_t)m * K_DIM + kb * 128 + lane * 2;
    float2 v = *(const float2*)(x + base);
    float amax = fmaxf(fabsf(v.x), fabsf(v.y));
    #pragma unroll
    for (int o = 32; o >= 1; o >>= 1) amax = fmaxf(amax, __shfl_xor(amax, o));
    float s = amax / 448.0f;          // IEEE div, matches jnp exactly
    uchar2 q;
    q.x = to_fp8(v.x / s);
    q.y = to_fp8(v.y / s);
    *(uchar2*)(xq + base) = q;
    if (lane == 0) saT[(size_t)kb * M + m] = s;
}

// ---------------- weight quant ----------------
__global__ __launch_bounds__(256) void w_quant_kernel(
    const float* __restrict__ w, uint8_t* __restrict__ wq)
{
    size_t i = ((size_t)blockIdx.x * 256 + threadIdx.x) * 4;
    float4 v = *(const float4*)(w + i);
    uchar4 q;
    q.x = to_fp8(v.x); q.y = to_fp8(v.y); q.z = to_fp8(v.z); q.w = to_fp8(v.w);
    *(uchar4*)(wq + i) = q;
}

// ---------------- MX fp8 GEMM: 256x256, BK=128, dbuf, 4 pacing phases (no sched pins) ----------------
// LDS per buffer: A 32K | B 32K | scales 1K -> 66560 B; x2 = 133120 B (1 block/CU)
#define LSA(b) ((b) * 66560)
#define LSB(b) ((b) * 66560 + 32768)
#define LSS(b) ((b) * 66560 + 65536)

__global__ __launch_bounds__(512, 1) void fp8_gemm_mx8(
    const uint8_t* __restrict__ Aq, const uint8_t* __restrict__ Bq,
    const float* __restrict__ saT, const float* __restrict__ wscale,
    float* __restrict__ C, int M)
{
    __shared__ __align__(16) uint8_t lds[133120];

    const int t    = threadIdx.x;
    const int lane = t & 63;
    const int lr   = lane & 15;
    const int lk   = lane >> 4;          // 0..3 -> k sub-block of 32
    const int wid  = t >> 6;
    const int wm   = wid >> 2;           // 0..1 : wave row half (128 rows)
    const int wn   = wid & 3;            // 0..3 : wave col quarter (64 cols)

    const int gridN = N_DIM / 256;       // 16
    int nwg = (M / 256) * gridN;         // 512, %8==0
    int cpx = nwg >> 3;
    int bid = blockIdx.x;
    int swz = (bid & 7) * cpx + (bid >> 3);   // bijective XCD swizzle
    const int m0 = (swz / gridN) * 256;
    const int n0 = (swz % gridN) * 256;
    const int nbI = ((n0 >> 7) + (wn >> 1)) * NKB;  // wscale row for this wave

    // staging map (proven R3/R5/R6): thread t -> row srow, phys 16B chunk (t&7);
    // source logical chunk ((t&7)^(srow&7)) => phys_chunk = logical ^ (row&7)
    const int srow = t >> 3;                       // 0..63 per pass
    const int scol = ((t & 7) ^ (srow & 7)) * 16;
    const uint8_t* gA = Aq + (size_t)(m0 + srow) * K_DIM + scol;
    const uint8_t* gB = Bq + (size_t)(n0 + srow) * K_DIM + scol;
    const int ldst = t * 16;                       // 8 KB per pass

    // fragment read swizzle: (row&7)==(lr&7)
    const int fsw = (lr & 7) << 4;
    const int c0  = (lk * 32) ^ fsw;

    f32x4 acc[8][4] = {};
    const f32x4 vzero = {0.f, 0.f, 0.f, 0.f};

    // ---- prologue: stage K-block 0 + scales into buf 0 ----
    #pragma unroll
    for (int j = 0; j < 4; ++j) {
        GLOAD_LDS16(gA + (size_t)j * 64 * K_DIM, &lds[LSA(0) + j * 8192 + ldst]);
        GLOAD_LDS16(gB + (size_t)j * 64 * K_DIM, &lds[LSB(0) + j * 8192 + ldst]);
    }
    if (wid < 4)
        GLOAD_LDS4(saT + m0 + wid * 64 + lane, &lds[LSS(0) + wid * 256 + lane * 4]);
    asm volatile("s_waitcnt vmcnt(0)" ::: "memory");
    __builtin_amdgcn_s_barrier();

    #pragma unroll 2
    for (int kb = 0; kb < NKB; ++kb) {
        const int cur = kb & 1;
        const int nxt = cur ^ 1;
        const int aB = LSA(cur), bB = LSB(cur), sB = LSS(cur);
        const int stage = (kb < NKB - 1);
        const size_t ko = (size_t)(kb + 1) * 128;
        const float rw = wscale[nbI + kb];        // wave-uniform scalar load

        i32x8 af[4], bf0[2], bf1[2];

        // helper lambdas (inlined, compile-time indices only)
#define LOAD_A(mh_) do {                                                       \
        _Pragma("unroll") for (int mi = 0; mi < 4; ++mi) {                     \
            int rb = aB + (wm * 128 + (mh_) * 64 + mi * 16 + lr) * 128;        \
            i32x4 lo = *(const i32x4*)&lds[rb + c0];                           \
            i32x4 hi = *(const i32x4*)&lds[rb + (c0 ^ 16)];                    \
            af[mi] = __builtin_shufflevector(lo, hi, 0, 1, 2, 3, 4, 5, 6, 7);  \
        } } while (0)
#define LOAD_B(dst_, nh_) do {                                                 \
        _Pragma("unroll") for (int ni = 0; ni < 2; ++ni) {                     \
            int rb = bB + (wn * 64 + (nh_) * 32 + ni * 16 + lr) * 128;         \
            i32x4 lo = *(const i32x4*)&lds[rb + c0];                           \
            i32x4 hi = *(const i32x4*)&lds[rb + (c0 ^ 16)];                    \
            dst_[ni] = __builtin_shufflevector(lo, hi, 0, 1, 2, 3, 4, 5, 6, 7);\
        } } while (0)
#define COMPUTE(mh_, nh_, bfr_) do {                                           \
        __builtin_amdgcn_s_setprio(1);                                         \
        _Pragma("unroll") for (int mi = 0; mi < 4; ++mi) {                     \
            f32x4 s4 = *(const f32x4*)&lds[sB + (wm * 128 + (mh_) * 64 + mi * 16 + lk * 4) * 4]; \
            f32x4 sc = s4 * rw;                                                \
            f32x4 bs0 = __builtin_amdgcn_mfma_scale_f32_16x16x128_f8f6f4(      \
                af[mi], bfr_[0], vzero, 0, 0, 0, 0x7F7F7F7F, 0, 0x7F7F7F7F);   \
            f32x4 bs1 = __builtin_amdgcn_mfma_scale_f32_16x16x128_f8f6f4(      \
                af[mi], bfr_[1], vzero, 0, 0, 0, 0x7F7F7F7F, 0, 0x7F7F7F7F);   \
            acc[(mh_) * 4 + mi][(nh_) * 2 + 0] += bs0 * sc;                    \
            acc[(mh_) * 4 + mi][(nh_) * 2 + 1] += bs1 * sc;                    \
        }                                                                      \
        __builtin_amdgcn_s_setprio(0);                                         \
    } while (0)

        // ---- phase 0: (mh0,nh0); stage A-half0 of kb+1 ----
        LOAD_A(0);
        LOAD_B(bf0, 0);
        if (stage) {
            GLOAD_LDS16(gA + ko, &lds[LSA(nxt) + ldst]);
            GLOAD_LDS16(gA + ko + (size_t)64 * K_DIM, &lds[LSA(nxt) + 8192 + ldst]);
        }
        __builtin_amdgcn_s_barrier();
        COMPUTE(0, 0, bf0);
        __builtin_amdgcn_s_barrier();

        // ---- phase 1: (mh0,nh1); stage A-half1 ----
        LOAD_B(bf1, 1);
        if (stage) {
            GLOAD_LDS16(gA + ko + (size_t)128 * K_DIM, &lds[LSA(nxt) + 16384 + ldst]);
            GLOAD_LDS16(gA + ko + (size_t)192 * K_DIM, &lds[LSA(nxt) + 24576 + ldst]);
        }
        __builtin_amdgcn_s_barrier();
        COMPUTE(0, 1, bf1);
        __builtin_amdgcn_s_barrier();

        // ---- phase 2: (mh1,nh0); stage B halves + scales ----
        LOAD_A(1);
        if (stage) {
            #pragma unroll
            for (int j = 0; j < 4; ++j)
                GLOAD_LDS16(gB + ko + (size_t)j * 64 * K_DIM,
                            &lds[LSB(nxt) + j * 8192 + ldst]);
            if (wid < 4)
                GLOAD_LDS4(saT + (size_t)(kb + 1) * M + m0 + wid * 64 + lane,
                           &lds[LSS(nxt) + wid * 256 + lane * 4]);
        }
        __builtin_amdgcn_s_barrier();
        COMPUTE(1, 0, bf0);
        __builtin_amdgcn_s_barrier();

        // ---- phase 3: (mh1,nh1); drain staging before buffer swap ----
        __builtin_amdgcn_s_barrier();
        COMPUTE(1, 1, bf1);
        asm volatile("s_waitcnt vmcnt(0)" ::: "memory");
        __builtin_amdgcn_s_barrier();

#undef LOAD_A
#undef LOAD_B
#undef COMPUTE
    }

    // ---- epilogue: C/D layout col=lane&15, row=lk*4+j (verified R1/R3/R6) ----
    #pragma unroll
    for (int q = 0; q < 8; ++q) {
        int mh = q >> 2, mi = q & 3;
        #pragma unroll
        for (int j = 0; j < 4; ++j) {
            int m = m0 + wm * 128 + mh * 64 + mi * 16 + lk * 4 + j;
            float* crow = C + (size_t)m * N_DIM + n0 + wn * 64;
            #pragma unroll
            for (int ni = 0; ni < 4; ++ni) {
                int nh = ni >> 1, nn = ni & 1;
                crow[nh * 32 + nn * 16 + lr] = acc[q][nh * 2 + nn][j];
            }
        }
    }
}

extern "C" void kernel_launch(void* const* d_in, const int* in_sizes, int n_in,
                              void* d_out, int out_size, void* d_ws, size_t ws_size,
                              hipStream_t stream) {
    const float* x      = (const float*)d_in[0];
    const float* w      = (const float*)d_in[1];
    const float* wscale = (const float*)d_in[2];
    float* out = (float*)d_out;
    int M = in_sizes[0] / K_DIM;                  // 8192

    // workspace: xq [M*K] | wq [N*K] | saT [32*M]
    uint8_t* xq  = (uint8_t*)d_ws;
    uint8_t* wq  = xq + (size_t)M * K_DIM;
    float*   saT = (float*)(wq + (size_t)N_DIM * K_DIM);

    act_quant_kernel<<<M * NKB / 4, 256, 0, stream>>>(x, xq, saT, M);
    w_quant_kernel<<<((size_t)N_DIM * K_DIM) / 1024, 256, 0, stream>>>(w, wq);

    int nwg = (M / 256) * (N_DIM / 256);
    fp8_gemm_mx8<<<nwg, 512, 0, stream>>>(xq, wq, saT, wscale, out, M);
}

// Round 10
// 236.073 us; speedup vs baseline: 9.8559x; 7.8202x over previous
//
#include <hip/hip_runtime.h>
#include <hip/hip_fp8.h>
#include <stdint.h>

#define K_DIM 4096
#define N_DIM 4096
#define NKB   32     // number of 128-wide K scale blocks

using f32x4 = __attribute__((ext_vector_type(4))) float;
using i32x4 = __attribute__((ext_vector_type(4))) int;
using i32x8 = __attribute__((ext_vector_type(8))) int;

#define GLOAD_LDS16(g, l)                                                      \
    __builtin_amdgcn_global_load_lds(                                          \
        (const __attribute__((address_space(1))) unsigned int*)(g),            \
        (__attribute__((address_space(3))) unsigned int*)(l), 16, 0, 0)
#define GLOAD_LDS4(g, l)                                                       \
    __builtin_amdgcn_global_load_lds(                                          \
        (const __attribute__((address_space(1))) unsigned int*)(g),            \
        (__attribute__((address_space(3))) unsigned int*)(l), 4, 0, 0)

__device__ __forceinline__ uint8_t to_fp8(float v) {
    __hip_fp8_e4m3 q(v);   // OCP e4m3fn, RNE saturating
    return (uint8_t)q.__x;
}

// ---------------- activation quant: one wave per (m, kb); scales TRANSPOSED saT[kb][m] ----------------
__global__ __launch_bounds__(256) void act_quant_kernel(
    const float* __restrict__ x, uint8_t* __restrict__ xq,
    float* __restrict__ saT, int M)
{
    int gw   = blockIdx.x * 4 + (threadIdx.x >> 6);
    int lane = threadIdx.x & 63;
    int m    = gw >> 5;
    int kb   = gw & 31;
    size_t base = (size_t)m * K_DIM + kb * 128 + lane * 2;
    float2 v = *(const float2*)(x + base);
    float amax = fmaxf(fabsf(v.x), fabsf(v.y));
    #pragma unroll
    for (int o = 32; o >= 1; o >>= 1) amax = fmaxf(amax, __shfl_xor(amax, o));
    float s = amax / 448.0f;          // IEEE div, matches jnp exactly
    uchar2 q;
    q.x = to_fp8(v.x / s);
    q.y = to_fp8(v.y / s);
    *(uchar2*)(xq + base) = q;
    if (lane == 0) saT[(size_t)kb * M + m] = s;
}

// ---------------- weight quant ----------------
__global__ __launch_bounds__(256) void w_quant_kernel(
    const float* __restrict__ w, uint8_t* __restrict__ wq)
{
    size_t i = ((size_t)blockIdx.x * 256 + threadIdx.x) * 4;
    float4 v = *(const float4*)(w + i);
    uchar4 q;
    q.x = to_fp8(v.x); q.y = to_fp8(v.y); q.z = to_fp8(v.z); q.w = to_fp8(v.w);
    *(uchar4*)(wq + i) = q;
}

// ---------------- ratio pre-kernel (verified R2/R8): telescoping rescale factors ----------------
// ra[sb][m]  = sb==0 ? 1 : saT[sb-1][m]/saT[sb][m]
// rwr[sb][nb]= sb==0 ? 1 : ws[nb][sb-1]/ws[nb][sb]
__global__ __launch_bounds__(256) void ratio_kernel(
    const float* __restrict__ saT, const float* __restrict__ ws,
    float* __restrict__ ra, float* __restrict__ rwr, int M)
{
    int idx = blockIdx.x * 256 + threadIdx.x;
    if (idx < 32 * M) {
        int sb = idx / M, m = idx - sb * M;
        float v = 1.0f;
        if (sb >= 1) v = saT[(size_t)(sb - 1) * M + m] / saT[(size_t)sb * M + m];
        ra[idx] = v;
    }
    if (idx < 32 * 32) {
        int sb = idx >> 5, nb = idx & 31;
        float v = 1.0f;
        if (sb >= 1) v = ws[nb * NKB + sb - 1] / ws[nb * NKB + sb];
        rwr[idx] = v;
    }
}

// ---------------- MX fp8 GEMM: 256x256 tile, BK=128, dbuf (R6 body), direct-accumulate ----------------
// LDS per buffer: A 32K | B 32K | ratios 1K -> 66560 B; x2 = 133120 B (1 block/CU)
#define LSA(b) ((b) * 66560)
#define LSB(b) ((b) * 66560 + 32768)
#define LSS(b) ((b) * 66560 + 65536)

__global__ __launch_bounds__(512, 1) void fp8_gemm_mx9(
    const uint8_t* __restrict__ Aq, const uint8_t* __restrict__ Bq,
    const float* __restrict__ saT, const float* __restrict__ ra,
    const float* __restrict__ rwr, const float* __restrict__ wscale,
    float* __restrict__ C, int M)
{
    __shared__ __align__(16) uint8_t lds[133120];

    const int t    = threadIdx.x;
    const int lane = t & 63;
    const int lr   = lane & 15;
    const int lk   = lane >> 4;          // 0..3 -> k sub-block of 32
    const int wid  = t >> 6;
    const int wm   = wid >> 2;           // 0..1 : wave row half (128 rows)
    const int wn   = wid & 3;            // 0..3 : wave col quarter (64 cols)

    const int gridN = N_DIM / 256;       // 16
    int nwg = (M / 256) * gridN;         // 512, %8==0
    int cpx = nwg >> 3;
    int bid = blockIdx.x;
    int swz = (bid & 7) * cpx + (bid >> 3);   // bijective XCD swizzle
    const int m0 = (swz / gridN) * 256;
    const int n0 = (swz % gridN) * 256;
    const int nb = (n0 >> 7) + (wn >> 1);     // global wscale row (0..31)

    // staging map (proven R3/R5/R6): thread t -> row srow, phys 16B chunk (t&7);
    // source logical chunk ((t&7)^(srow&7)) => phys_chunk = logical ^ (row&7)
    const int srow = t >> 3;                       // 0..63 per pass
    const int scol = ((t & 7) ^ (srow & 7)) * 16;
    const uint8_t* gA = Aq + (size_t)(m0 + srow) * K_DIM + scol;
    const uint8_t* gB = Bq + (size_t)(n0 + srow) * K_DIM + scol;
    const int ldst = t * 16;                       // 8 KB per pass

    // fragment read swizzle: (row&7)==(lr&7)
    const int fsw = (lr & 7) << 4;
    const int c0  = (lk * 32) ^ fsw;

#define STAGE(buf, kbi) do {                                                   \
    size_t ko_ = (size_t)(kbi) * 128;                                          \
    _Pragma("unroll") for (int j = 0; j < 4; ++j) {                            \
        GLOAD_LDS16(gA + ko_ + (size_t)j * 64 * K_DIM,                         \
                    &lds[LSA(buf) + j * 8192 + ldst]);                         \
        GLOAD_LDS16(gB + ko_ + (size_t)j * 64 * K_DIM,                         \
                    &lds[LSB(buf) + j * 8192 + ldst]);                         \
    }                                                                          \
    if (wid < 4)                                                               \
        GLOAD_LDS4(ra + (size_t)(kbi) * M + m0 + wid * 64 + lane,              \
                   &lds[LSS(buf) + wid * 256 + lane * 4]);                     \
} while (0)

    f32x4 acc[8][4] = {};

    // ---- prologue: stage K-block 0 + ratio row 0 (all 1.0) into buf 0 ----
    STAGE(0, 0);
    asm volatile("s_waitcnt vmcnt(0)" ::: "memory");
    __builtin_amdgcn_s_barrier();

    #pragma unroll 2
    for (int kb = 0; kb < NKB; ++kb) {
        const int cur = kb & 1;
        // ---- issue next tile's staging FIRST (overlaps compute below) ----
        if (kb < NKB - 1) STAGE(cur ^ 1, kb + 1);

        const int aB = LSA(cur), bB = LSB(cur), sB = LSS(cur);
        const float rwc = rwr[kb * 32 + nb];      // wave-uniform ratio (1.0 at kb=0)

        // ---- B fragments once (4 x 32B), A per 64-row half (caps VGPR) ----
        i32x8 bf[4];
        #pragma unroll
        for (int ni = 0; ni < 4; ++ni) {
            int rb = bB + (wn * 64 + ni * 16 + lr) * 128;
            i32x4 lo = *(const i32x4*)&lds[rb + c0];
            i32x4 hi = *(const i32x4*)&lds[rb + (c0 ^ 16)];
            bf[ni] = __builtin_shufflevector(lo, hi, 0, 1, 2, 3, 4, 5, 6, 7);
        }
        #pragma unroll
        for (int mh = 0; mh < 2; ++mh) {
            i32x8 af[4];
            #pragma unroll
            for (int mi = 0; mi < 4; ++mi) {
                int rb = aB + (wm * 128 + mh * 64 + mi * 16 + lr) * 128;
                i32x4 lo = *(const i32x4*)&lds[rb + c0];
                i32x4 hi = *(const i32x4*)&lds[rb + (c0 ^ 16)];
                af[mi] = __builtin_shufflevector(lo, hi, 0, 1, 2, 3, 4, 5, 6, 7);
            }
            // ---- telescoped rescale of this half, then MFMA accumulates in place ----
            #pragma unroll
            for (int mi = 0; mi < 4; ++mi) {
                f32x4 ra4 = *(const f32x4*)&lds[sB + (wm * 128 + mh * 64 + mi * 16 + lk * 4) * 4];
                f32x4 sc = ra4 * rwc;
                #pragma unroll
                for (int ni = 0; ni < 4; ++ni)
                    acc[mh * 4 + mi][ni] *= sc;
                #pragma unroll
                for (int ni = 0; ni < 4; ++ni)
                    acc[mh * 4 + mi][ni] =
                        __builtin_amdgcn_mfma_scale_f32_16x16x128_f8f6f4(
                            af[mi], bf[ni], acc[mh * 4 + mi][ni],
                            0, 0, 0, 0x7F7F7F7F, 0, 0x7F7F7F7F);   // unit e8m0
            }
        }

        // ---- single drain + barrier per K-block ----
        asm volatile("s_waitcnt vmcnt(0)" ::: "memory");
        __builtin_amdgcn_s_barrier();
    }
#undef STAGE

    // ---- epilogue: out = acc * s31[m] * ws[nb][31]; C/D layout col=lane&15, row=lk*4+j ----
    const float ws31 = wscale[nb * NKB + 31];
    #pragma unroll
    for (int q = 0; q < 8; ++q) {
        int mh = q >> 2, mi = q & 3;
        f32x4 s31 = *(const f32x4*)(saT + (size_t)31 * M + m0 + wm * 128 + mh * 64 + mi * 16 + lk * 4);
        f32x4 sc = s31 * ws31;
        #pragma unroll
        for (int j = 0; j < 4; ++j) {
            int m = m0 + wm * 128 + mh * 64 + mi * 16 + lk * 4 + j;
            float* crow = C + (size_t)m * N_DIM + n0 + wn * 64;
            #pragma unroll
            for (int ni = 0; ni < 4; ++ni)
                crow[ni * 16 + lr] = acc[q][ni][j] * sc[j];
        }
    }
}

extern "C" void kernel_launch(void* const* d_in, const int* in_sizes, int n_in,
                              void* d_out, int out_size, void* d_ws, size_t ws_size,
                              hipStream_t stream) {
    const float* x      = (const float*)d_in[0];
    const float* w      = (const float*)d_in[1];
    const float* wscale = (const float*)d_in[2];
    float* out = (float*)d_out;
    int M = in_sizes[0] / K_DIM;                  // 8192

    // workspace: xq [M*K] | wq [N*K] | saT [32*M] | ra [32*M] | rwr [32*32]
    uint8_t* xq  = (uint8_t*)d_ws;
    uint8_t* wq  = xq + (size_t)M * K_DIM;
    float*   saT = (float*)(wq + (size_t)N_DIM * K_DIM);
    float*   ra  = saT + (size_t)NKB * M;
    float*   rwr = ra + (size_t)NKB * M;

    act_quant_kernel<<<M * NKB / 4, 256, 0, stream>>>(x, xq, saT, M);
    w_quant_kernel<<<((size_t)N_DIM * K_DIM) / 1024, 256, 0, stream>>>(w, wq);
    ratio_kernel<<<(32 * M + 255) / 256, 256, 0, stream>>>(saT, wscale, ra, rwr, M);

    int nwg = (M / 256) * (N_DIM / 256);
    fp8_gemm_mx9<<<nwg, 512, 0, stream>>>(xq, wq, saT, ra, rwr, wscale, out, M);
}